// Round 6
// baseline (482.500 us; speedup 1.0000x reference)
//
#include <hip/hip_runtime.h>

#define BATCH 16
#define CH    64
#define TLEN  200
#define NP    30
#define HID   128
#define G4    512            // 4*HID
#define NSEQ  (BATCH * NP)   // 480

typedef _Float16 f16x2 __attribute__((ext_vector_type(2)));
typedef _Float16 half8 __attribute__((ext_vector_type(8)));
typedef float    f32x4 __attribute__((ext_vector_type(4)));

#if __has_builtin(__builtin_amdgcn_fdot2)
#define FDOT2(w, h, a) __builtin_amdgcn_fdot2((w), (h), (a), false)
#else
#define FDOT2(w, h, a) ((a) + (float)(w)[0] * (float)(h)[0] + (float)(w)[1] * (float)(h)[1])
#endif

__device__ __forceinline__ float sigm_fast(float x) {
    return __builtin_amdgcn_rcpf(1.0f + __expf(-x));
}
__device__ __forceinline__ float tanh_fast(float x) {
    float xc = fminf(15.0f, fmaxf(-15.0f, x));
    float e = __expf(2.0f * xc);
    return (e - 1.0f) * __builtin_amdgcn_rcpf(e + 1.0f);
}

// ---------------------------------------------------------------------------
// Phase 1 (unchanged from R5): xg[n][t][g] = dot(x[b,:,t,p], W_ih[g,:]) + bias
// ---------------------------------------------------------------------------
template <typename XT>
__global__ __launch_bounds__(512) void xg_kernel(
    const float* __restrict__ x, const float* __restrict__ W_ih,
    const float* __restrict__ b_ih, const float* __restrict__ b_hh,
    XT* __restrict__ xg)
{
    const int t0  = blockIdx.x * 2;
    const int b   = blockIdx.y;
    const int tid = threadIdx.x;

    __shared__ float ws[CH][G4];
    __shared__ float xs[CH][64];

    {
        const float4* W4 = (const float4*)W_ih;
#pragma unroll
        for (int i = 0; i < 16; ++i) {
            float4 v = W4[i * 512 + tid];
            int base = 4 * (i * 512 + tid);
            int g = base >> 6;
            int k = base & 63;
            ws[k][g] = v.x; ws[k + 1][g] = v.y; ws[k + 2][g] = v.z; ws[k + 3][g] = v.w;
        }
    }
    {
        const int c = tid >> 3, sub = tid & 7;
#pragma unroll
        for (int tt = 0; tt < 2; ++tt) {
            const float* xr = x + ((size_t)(b * CH + c) * TLEN + (t0 + tt)) * NP;
            for (int p = sub; p < NP; p += 8) xs[c][tt * 32 + p] = xr[p];
        }
    }

    const int gq   = tid & 63;
    const int posq = tid >> 6;
    const int pos0 = posq * 8;

    float bias[8];
#pragma unroll
    for (int j = 0; j < 8; ++j) {
        int g = gq + 64 * j;
        bias[j] = b_ih[g] + b_hh[g];
    }
    __syncthreads();

    float acc[8][8];
#pragma unroll
    for (int j = 0; j < 8; ++j)
#pragma unroll
        for (int i = 0; i < 8; ++i) acc[j][i] = 0.f;

#pragma unroll 4
    for (int k = 0; k < CH; ++k) {
        float w[8];
#pragma unroll
        for (int j = 0; j < 8; ++j) w[j] = ws[k][gq + 64 * j];
        float4 xlo = *(const float4*)&xs[k][pos0];
        float4 xhi = *(const float4*)&xs[k][pos0 + 4];
        float xv[8] = {xlo.x, xlo.y, xlo.z, xlo.w, xhi.x, xhi.y, xhi.z, xhi.w};
#pragma unroll
        for (int j = 0; j < 8; ++j)
#pragma unroll
            for (int i = 0; i < 8; ++i) acc[j][i] = fmaf(w[j], xv[i], acc[j][i]);
    }

#pragma unroll
    for (int i = 0; i < 8; ++i) {
        int pos = pos0 + i;
        int tt = pos >> 5, p = pos & 31;
        if (p >= NP) continue;
        int n = b * NP + p;
        size_t rowbase = ((size_t)n * TLEN + (t0 + tt)) * G4;
#pragma unroll
        for (int j = 0; j < 8; ++j) {
            int g = gq + 64 * j;
            xg[rowbase + g] = (XT)(acc[j][i] + bias[j]);
        }
    }
}

// ---------------------------------------------------------------------------
// Phase 2: MFMA LSTM. Block = 16 sequences (30 blocks). Wave w owns hid slice
// [16w,16w+16) of all 4 gate types: N-tiles {w, 8+w, 16+w, 24+w}.
// B-frags = W_hh rows in 64 VGPRs (loaded from global once; waves_per_eu(2,2)
// pins occupancy so the allocator has no reason to re-materialize them — the
// R1/R2 pathology). Per step: 4 ds_read_b128 (h), 16 MFMA with xg as the
// C-operand, in-register gate update, 4 ds_write_b16 (h'), ONE barrier
// (h is double-buffered).
// ---------------------------------------------------------------------------
template <typename XT>
__global__ __attribute__((amdgpu_flat_work_group_size(512, 512)))
__attribute__((amdgpu_waves_per_eu(2, 2)))
void lstm_kernel(
    const XT* __restrict__ xg, const float* __restrict__ W_hh,
    const float* __restrict__ W_fc, const float* __restrict__ b_fc,
    float* __restrict__ out)
{
    const int blk = blockIdx.x;       // 0..29
    const int n0  = blk * 16;
    const int tid = threadIdx.x;
    const int w   = tid >> 6;         // wave 0..7
    const int l   = tid & 63;
    const int l15 = l & 15;           // C/D col = hid-in-tile; A/B outer idx
    const int quad = l >> 4;          // C/D rows quad*4..quad*4+3; k-offset quad*8
    const int gidx = w * 16 + l15;    // hid index this lane updates

    __shared__ _Float16 hbuf[2][16][HID];   // 8 KB double-buffered h (fp16)

    for (int i = tid; i < 16 * HID; i += 512)
        hbuf[0][i >> 7][i & 127] = (_Float16)0;

    // B-frags: lane l of tile (gate-type q) holds W_hh[q*128 + gidx][kt*32 + quad*8 + j]
    half8 bfrag[4][4];
#pragma unroll
    for (int q = 0; q < 4; ++q) {
        const float* wrow = W_hh + (size_t)(q * 128 + gidx) * HID;
#pragma unroll
        for (int kt = 0; kt < 4; ++kt) {
            const float4* p = (const float4*)(wrow + kt * 32 + quad * 8);
            float4 f0 = p[0], f1 = p[1];
            bfrag[q][kt] = (half8){(_Float16)f0.x, (_Float16)f0.y, (_Float16)f0.z, (_Float16)f0.w,
                                   (_Float16)f1.x, (_Float16)f1.y, (_Float16)f1.z, (_Float16)f1.w};
        }
    }

    // xg stream: 4 row pointers (seq = n0 + quad*4 + r), gate offsets q*128 imm
    const XT* px[4];
#pragma unroll
    for (int r = 0; r < 4; ++r)
        px[r] = xg + (size_t)(n0 + quad * 4 + r) * TLEN * G4 + gidx;

    float xgv[4][4];   // [q][r]
#pragma unroll
    for (int r = 0; r < 4; ++r) {
#pragma unroll
        for (int q = 0; q < 4; ++q) xgv[q][r] = (float)px[r][q * 128];
        px[r] += G4;
    }

    float cst[4] = {0.f, 0.f, 0.f, 0.f};   // c-state: 4 seqs x 1 hid
    __syncthreads();

    for (int t = 0; t < TLEN; ++t) {
        // A-frags: h[m = l15][k = kt*32 + quad*8 ..+8] from current buffer
        half8 afrag[4];
#pragma unroll
        for (int kt = 0; kt < 4; ++kt)
            afrag[kt] = *(const half8*)&hbuf[t & 1][l15][kt * 32 + quad * 8];

        // C init = xg (pre-activations)
        f32x4 acc0 = {xgv[0][0], xgv[0][1], xgv[0][2], xgv[0][3]};
        f32x4 acc1 = {xgv[1][0], xgv[1][1], xgv[1][2], xgv[1][3]};
        f32x4 acc2 = {xgv[2][0], xgv[2][1], xgv[2][2], xgv[2][3]};
        f32x4 acc3 = {xgv[3][0], xgv[3][1], xgv[3][2], xgv[3][3]};

        // prefetch next step's xg (hides L2/L3 latency under MFMA+update)
        if (t + 1 < TLEN) {
#pragma unroll
            for (int r = 0; r < 4; ++r) {
#pragma unroll
                for (int q = 0; q < 4; ++q) xgv[q][r] = (float)px[r][q * 128];
                px[r] += G4;
            }
        }

#pragma unroll
        for (int kt = 0; kt < 4; ++kt) {
            acc0 = __builtin_amdgcn_mfma_f32_16x16x32_f16(afrag[kt], bfrag[0][kt], acc0, 0, 0, 0);
            acc1 = __builtin_amdgcn_mfma_f32_16x16x32_f16(afrag[kt], bfrag[1][kt], acc1, 0, 0, 0);
            acc2 = __builtin_amdgcn_mfma_f32_16x16x32_f16(afrag[kt], bfrag[2][kt], acc2, 0, 0, 0);
            acc3 = __builtin_amdgcn_mfma_f32_16x16x32_f16(afrag[kt], bfrag[3][kt], acc3, 0, 0, 0);
        }

        // update: lane holds gates i,f,g,o for seqs quad*4+r, hid gidx
#pragma unroll
        for (int r = 0; r < 4; ++r) {
            float ii = sigm_fast(acc0[r]);
            float ff = sigm_fast(acc1[r]);
            float gg = tanh_fast(acc2[r]);
            float oo = sigm_fast(acc3[r]);
            float cn = ff * cst[r] + ii * gg;
            cst[r] = cn;
            hbuf[(t + 1) & 1][quad * 4 + r][gidx] = (_Float16)(oo * tanh_fast(cn));
        }
        __syncthreads();
    }

    // FC epilogue: final h is in hbuf[TLEN & 1] == hbuf[0]
    for (int i = tid; i < 16 * CH; i += 512) {
        const int s = i >> 6, ch = i & 63;
        const float4* wf = (const float4*)(W_fc + (size_t)ch * HID);
        float a = b_fc[ch];
#pragma unroll
        for (int j = 0; j < 32; ++j) {
            float4 w4 = wf[j];
            a += w4.x * (float)hbuf[0][s][4 * j]
               + w4.y * (float)hbuf[0][s][4 * j + 1]
               + w4.z * (float)hbuf[0][s][4 * j + 2]
               + w4.w * (float)hbuf[0][s][4 * j + 3];
        }
        out[(size_t)(n0 + s) * CH + ch] = a;
    }
}

extern "C" void kernel_launch(void* const* d_in, const int* in_sizes, int n_in,
                              void* d_out, int out_size, void* d_ws, size_t ws_size,
                              hipStream_t stream) {
    (void)in_sizes; (void)n_in; (void)out_size;
    const float* x    = (const float*)d_in[0];
    const float* W_ih = (const float*)d_in[1];
    const float* W_hh = (const float*)d_in[2];
    const float* b_ih = (const float*)d_in[3];
    const float* b_hh = (const float*)d_in[4];
    const float* W_fc = (const float*)d_in[5];
    const float* b_fc = (const float*)d_in[6];
    float* out = (float*)d_out;

    const size_t need_f32 = (size_t)NSEQ * TLEN * G4 * sizeof(float);  // 196.6 MB
    if (ws_size >= need_f32) {
        float* xg = (float*)d_ws;
        xg_kernel<float><<<dim3(TLEN / 2, BATCH), 512, 0, stream>>>(x, W_ih, b_ih, b_hh, xg);
        lstm_kernel<float><<<NSEQ / 16, 512, 0, stream>>>(xg, W_hh, W_fc, b_fc, out);
    } else {
        _Float16* xg = (_Float16*)d_ws;
        xg_kernel<_Float16><<<dim3(TLEN / 2, BATCH), 512, 0, stream>>>(x, W_ih, b_ih, b_hh, xg);
        lstm_kernel<_Float16><<<NSEQ / 16, 512, 0, stream>>>(xg, W_hh, W_fc, b_fc, out);
    }
}

// Round 7
// 457.285 us; speedup vs baseline: 1.0551x; 1.0551x over previous
//
#include <hip/hip_runtime.h>

#define BATCH 16
#define CH    64
#define TLEN  200
#define NP    30
#define HID   128
#define G4    512            // 4*HID
#define NSEQ  (BATCH * NP)   // 480
#define HROW  132            // hbuf row stride in halves: 264 B -> bank stride 2 -> conflict-free

typedef _Float16 half8 __attribute__((ext_vector_type(8)));
typedef float    f32x4 __attribute__((ext_vector_type(4)));

__device__ __forceinline__ float sigm_fast(float x) {
    return __builtin_amdgcn_rcpf(1.0f + __expf(-x));
}
__device__ __forceinline__ float tanh_fast(float x) {
    float xc = fminf(15.0f, fmaxf(-15.0f, x));
    float e = __expf(2.0f * xc);
    return (e - 1.0f) * __builtin_amdgcn_rcpf(e + 1.0f);
}

// ---------------------------------------------------------------------------
// Phase 1: xg[n][t][g] = dot(x[b,:,t,p], W_ih[g,:]) + bias.
// R7 change: ws padded to G4+1. Row stride 513 floats -> bank = (k + g) % 32,
// so the 16-lane staging write groups (which share g, k = 4*(lane&15)+j) go
// 2-way (free) instead of 16-way, and main-loop reads stay stride-1.
// ---------------------------------------------------------------------------
template <typename XT>
__global__ __launch_bounds__(512) void xg_kernel(
    const float* __restrict__ x, const float* __restrict__ W_ih,
    const float* __restrict__ b_ih, const float* __restrict__ b_hh,
    XT* __restrict__ xg)
{
    const int t0  = blockIdx.x * 2;
    const int b   = blockIdx.y;
    const int tid = threadIdx.x;

    __shared__ float ws[CH][G4 + 1];
    __shared__ float xs[CH][64];

    {
        const float4* W4 = (const float4*)W_ih;
#pragma unroll
        for (int i = 0; i < 16; ++i) {
            float4 v = W4[i * 512 + tid];
            int base = 4 * (i * 512 + tid);
            int g = base >> 6;
            int k = base & 63;
            ws[k][g] = v.x; ws[k + 1][g] = v.y; ws[k + 2][g] = v.z; ws[k + 3][g] = v.w;
        }
    }
    {
        const int c = tid >> 3, sub = tid & 7;
#pragma unroll
        for (int tt = 0; tt < 2; ++tt) {
            const float* xr = x + ((size_t)(b * CH + c) * TLEN + (t0 + tt)) * NP;
            for (int p = sub; p < NP; p += 8) xs[c][tt * 32 + p] = xr[p];
        }
    }

    const int gq   = tid & 63;
    const int posq = tid >> 6;
    const int pos0 = posq * 8;

    float bias[8];
#pragma unroll
    for (int j = 0; j < 8; ++j) {
        int g = gq + 64 * j;
        bias[j] = b_ih[g] + b_hh[g];
    }
    __syncthreads();

    float acc[8][8];
#pragma unroll
    for (int j = 0; j < 8; ++j)
#pragma unroll
        for (int i = 0; i < 8; ++i) acc[j][i] = 0.f;

#pragma unroll 4
    for (int k = 0; k < CH; ++k) {
        float w[8];
#pragma unroll
        for (int j = 0; j < 8; ++j) w[j] = ws[k][gq + 64 * j];
        float4 xlo = *(const float4*)&xs[k][pos0];
        float4 xhi = *(const float4*)&xs[k][pos0 + 4];
        float xv[8] = {xlo.x, xlo.y, xlo.z, xlo.w, xhi.x, xhi.y, xhi.z, xhi.w};
#pragma unroll
        for (int j = 0; j < 8; ++j)
#pragma unroll
            for (int i = 0; i < 8; ++i) acc[j][i] = fmaf(w[j], xv[i], acc[j][i]);
    }

#pragma unroll
    for (int i = 0; i < 8; ++i) {
        int pos = pos0 + i;
        int tt = pos >> 5, p = pos & 31;
        if (p >= NP) continue;
        int n = b * NP + p;
        size_t rowbase = ((size_t)n * TLEN + (t0 + tt)) * G4;
#pragma unroll
        for (int j = 0; j < 8; ++j) {
            int g = gq + 64 * j;
            xg[rowbase + g] = (XT)(acc[j][i] + bias[j]);
        }
    }
}

// ---------------------------------------------------------------------------
// Phase 2: MFMA LSTM. Block = 16 seqs (30 blocks). Wave w owns hid slice
// [16w,16w+16) of all 4 gate types. B-frags (W_hh) resident in 64 VGPRs.
// R7: (a) hbuf rows padded to 132 halves -> A-frag b128 reads and h b16
// writes are exactly conflict-free (R6: 5.76M conflict cycles);
// (b) xg prefetched TWO steps ahead (t-loop unrolled x2, two reg buffers,
// loads use offset immediates) -> ~2 step-times (>1400 cyc) of L3 cover.
// ---------------------------------------------------------------------------
template <typename XT>
__global__ __attribute__((amdgpu_flat_work_group_size(512, 512)))
__attribute__((amdgpu_waves_per_eu(2, 2)))
void lstm_kernel(
    const XT* __restrict__ xg, const float* __restrict__ W_hh,
    const float* __restrict__ W_fc, const float* __restrict__ b_fc,
    float* __restrict__ out)
{
    const int blk = blockIdx.x;       // 0..29
    const int n0  = blk * 16;
    const int tid = threadIdx.x;
    const int w   = tid >> 6;         // wave 0..7
    const int l   = tid & 63;
    const int l15 = l & 15;
    const int quad = l >> 4;
    const int gidx = w * 16 + l15;    // hid index this lane updates

    __shared__ _Float16 hbuf[2][16][HROW];   // padded, double-buffered h

    {
        _Float16* hz = &hbuf[0][0][0];
        for (int i = tid; i < 2 * 16 * HROW; i += 512) hz[i] = (_Float16)0;
    }

    // B-frags: lane l of gate-type q holds W_hh[q*128 + gidx][kt*32 + quad*8 + j]
    half8 bfrag[4][4];
#pragma unroll
    for (int q = 0; q < 4; ++q) {
        const float* wrow = W_hh + (size_t)(q * 128 + gidx) * HID;
#pragma unroll
        for (int kt = 0; kt < 4; ++kt) {
            const float4* p = (const float4*)(wrow + kt * 32 + quad * 8);
            float4 f0 = p[0], f1 = p[1];
            bfrag[q][kt] = (half8){(_Float16)f0.x, (_Float16)f0.y, (_Float16)f0.z, (_Float16)f0.w,
                                   (_Float16)f1.x, (_Float16)f1.y, (_Float16)f1.z, (_Float16)f1.w};
        }
    }

    // xg stream pointers: seq = n0 + quad*4 + r, element = gate q*128 + gidx
    const XT* px[4];
#pragma unroll
    for (int r = 0; r < 4; ++r)
        px[r] = xg + (size_t)(n0 + quad * 4 + r) * TLEN * G4 + gidx;

    float xga[4][4], xgb[4][4];   // [q][r] pre-activations for steps t, t+1
#pragma unroll
    for (int r = 0; r < 4; ++r)
#pragma unroll
        for (int q = 0; q < 4; ++q) {
            xga[q][r] = (float)px[r][q * 128];
            xgb[q][r] = (float)px[r][q * 128 + G4];
        }
#pragma unroll
    for (int r = 0; r < 4; ++r) px[r] += 2 * G4;   // now at t=2

    float cst[4] = {0.f, 0.f, 0.f, 0.f};
    __syncthreads();

    auto step = [&](const _Float16* hrd, _Float16* hwr,
                    float (&xgc)[4][4], bool pf, int pfofs) {
        half8 af[4];
#pragma unroll
        for (int kt = 0; kt < 4; ++kt)
            af[kt] = *(const half8*)(hrd + l15 * HROW + kt * 32 + quad * 8);

        f32x4 acc0 = {xgc[0][0], xgc[0][1], xgc[0][2], xgc[0][3]};
        f32x4 acc1 = {xgc[1][0], xgc[1][1], xgc[1][2], xgc[1][3]};
        f32x4 acc2 = {xgc[2][0], xgc[2][1], xgc[2][2], xgc[2][3]};
        f32x4 acc3 = {xgc[3][0], xgc[3][1], xgc[3][2], xgc[3][3]};

        if (pf) {   // prefetch this buffer's values for step t+2
#pragma unroll
            for (int r = 0; r < 4; ++r)
#pragma unroll
                for (int q = 0; q < 4; ++q)
                    xgc[q][r] = (float)px[r][q * 128 + pfofs];
        }

#pragma unroll
        for (int kt = 0; kt < 4; ++kt) {
            acc0 = __builtin_amdgcn_mfma_f32_16x16x32_f16(af[kt], bfrag[0][kt], acc0, 0, 0, 0);
            acc1 = __builtin_amdgcn_mfma_f32_16x16x32_f16(af[kt], bfrag[1][kt], acc1, 0, 0, 0);
            acc2 = __builtin_amdgcn_mfma_f32_16x16x32_f16(af[kt], bfrag[2][kt], acc2, 0, 0, 0);
            acc3 = __builtin_amdgcn_mfma_f32_16x16x32_f16(af[kt], bfrag[3][kt], acc3, 0, 0, 0);
        }

#pragma unroll
        for (int r = 0; r < 4; ++r) {
            float ii = sigm_fast(acc0[r]);
            float ff = sigm_fast(acc1[r]);
            float gg = tanh_fast(acc2[r]);
            float oo = sigm_fast(acc3[r]);
            float cn = ff * cst[r] + ii * gg;
            cst[r] = cn;
            hwr[(quad * 4 + r) * HROW + gidx] = (_Float16)(oo * tanh_fast(cn));
        }
        __syncthreads();
    };

    _Float16* hb0 = &hbuf[0][0][0];
    _Float16* hb1 = &hbuf[1][0][0];

    for (int t = 0; t < TLEN; t += 2) {
        step(hb0, hb1, xga, t + 2 < TLEN, 0);     // consumes t   (even)
        step(hb1, hb0, xgb, t + 3 < TLEN, G4);    // consumes t+1 (odd)
#pragma unroll
        for (int r = 0; r < 4; ++r) px[r] += 2 * G4;
    }

    // FC epilogue: final h (t=200, even) is in hbuf[0]
    for (int i = tid; i < 16 * CH; i += 512) {
        const int s = i >> 6, ch = i & 63;
        const float4* wf = (const float4*)(W_fc + (size_t)ch * HID);
        const _Float16* hrow = hb0 + s * HROW;
        float a = b_fc[ch];
#pragma unroll
        for (int j = 0; j < 32; ++j) {
            float4 w4 = wf[j];
            a += w4.x * (float)hrow[4 * j]     + w4.y * (float)hrow[4 * j + 1]
               + w4.z * (float)hrow[4 * j + 2] + w4.w * (float)hrow[4 * j + 3];
        }
        out[(size_t)(n0 + s) * CH + ch] = a;
    }
}

extern "C" void kernel_launch(void* const* d_in, const int* in_sizes, int n_in,
                              void* d_out, int out_size, void* d_ws, size_t ws_size,
                              hipStream_t stream) {
    (void)in_sizes; (void)n_in; (void)out_size;
    const float* x    = (const float*)d_in[0];
    const float* W_ih = (const float*)d_in[1];
    const float* W_hh = (const float*)d_in[2];
    const float* b_ih = (const float*)d_in[3];
    const float* b_hh = (const float*)d_in[4];
    const float* W_fc = (const float*)d_in[5];
    const float* b_fc = (const float*)d_in[6];
    float* out = (float*)d_out;

    const size_t need_f32 = (size_t)NSEQ * TLEN * G4 * sizeof(float);  // 196.6 MB
    if (ws_size >= need_f32) {
        float* xg = (float*)d_ws;
        xg_kernel<float><<<dim3(TLEN / 2, BATCH), 512, 0, stream>>>(x, W_ih, b_ih, b_hh, xg);
        lstm_kernel<float><<<NSEQ / 16, 512, 0, stream>>>(xg, W_hh, W_fc, b_fc, out);
    } else {
        _Float16* xg = (_Float16*)d_ws;
        xg_kernel<_Float16><<<dim3(TLEN / 2, BATCH), 512, 0, stream>>>(x, W_ih, b_ih, b_hh, xg);
        lstm_kernel<_Float16><<<NSEQ / 16, 512, 0, stream>>>(xg, W_hh, W_fc, b_fc, out);
    }
}